// Round 1
// baseline (539.162 us; speedup 1.0000x reference)
//
#include <hip/hip_runtime.h>

#define D_MODEL 2048
#define D_STATE 16
#define BATCH   2048

typedef __attribute__((ext_vector_type(8))) short bf16x8;
typedef __attribute__((ext_vector_type(4))) float f32x4;
typedef __attribute__((ext_vector_type(8))) unsigned short u16x8;

__device__ __forceinline__ unsigned short f2bf(float f) {
  unsigned u = __float_as_uint(f);
  u = (u + 0x7FFFu + ((u >> 16) & 1u)) >> 16;   // RNE
  return (unsigned short)u;
}

__device__ __forceinline__ void cvt8(const float* __restrict__ s, unsigned short* __restrict__ d) {
  float4 a = *(const float4*)s;
  float4 b = *(const float4*)(s + 4);
  u16x8 o;
  o[0] = f2bf(a.x); o[1] = f2bf(a.y); o[2] = f2bf(a.z); o[3] = f2bf(a.w);
  o[4] = f2bf(b.x); o[5] = f2bf(b.y); o[6] = f2bf(b.z); o[7] = f2bf(b.w);
  *(u16x8*)d = o;
}

// ---- prep: x->bf16, W_Delta->bf16, build padded [W_B;W_C;0...] bf16 (128 x 2048)
__global__ __launch_bounds__(256) void prep_kernel(
    const float* __restrict__ x, const float* __restrict__ wd,
    const float* __restrict__ wb, const float* __restrict__ wc,
    unsigned short* __restrict__ x_bf, unsigned short* __restrict__ w_bf,
    unsigned short* __restrict__ wbc) {
  int t = blockIdx.x * 256 + threadIdx.x;
  if (t < 524288) {                       // x: 4M elems / 8
    int base = t * 8;
    cvt8(x + base, x_bf + base);
  } else if (t < 1048576) {               // W_Delta: 4M elems / 8
    int base = (t - 524288) * 8;
    cvt8(wd + base, w_bf + base);
  } else {                                // wbc: 128*2048 elems / 8 = 32768 threads
    int i = (t - 1048576) * 8;
    int row = i >> 11, col = i & 2047;
    if (row < 16)      cvt8(wb + row * 2048 + col, wbc + i);
    else if (row < 32) cvt8(wc + (row - 16) * 2048 + col, wbc + i);
    else { u16x8 z = {0,0,0,0,0,0,0,0}; *(u16x8*)(wbc + i) = z; }
  }
}

// ---- bf16 MFMA GEMM, 128x128 tile, BK=32, 4 waves (2x2), m97-style staging.
// blockIdx.y in [0,16): Delta = softplus(x @ W_Delta^T + b)  (2048x2048, f32)
// blockIdx.y == 16   : BC    = x @ WBC^T                     (2048x128, f32)
__global__ __launch_bounds__(256) void gemm_kernel(
    const unsigned short* __restrict__ Abf,   // 2048 x 2048 (x, bf16)
    const unsigned short* __restrict__ Wbf,   // 2048 x 2048 (W_Delta, bf16)
    const unsigned short* __restrict__ WBC,   // 128 x 2048  (padded WB/WC, bf16)
    const float* __restrict__ bias,           // 2048
    float* __restrict__ Delta,                // 2048 x 2048
    float* __restrict__ BC) {                 // 2048 x 128
  __shared__ __align__(16) unsigned short lA[128 * 32];
  __shared__ __align__(16) unsigned short lB[128 * 32];

  const int tid = threadIdx.x;
  const bool isBC = (blockIdx.y == 16);
  const int brow = blockIdx.x * 128;
  const int bcol = isBC ? 0 : blockIdx.y * 128;
  const unsigned short* Bsrc = isBC ? WBC : (Wbf + (size_t)bcol * 2048);
  const unsigned short* Asrc = Abf + (size_t)brow * 2048;

  // staging geometry: byteoff = i*4096 + tid*16 over an 8192-B [128][32] bf16 tile
  const int r0 = (tid * 16) >> 6;          // row for call i=0 (i adds 64)
  const int c0 = ((tid * 16) & 63) >> 1;   // bf16 col within row
  const int ldsbase = (tid >> 6) << 10;    // wave-uniform byte base (wave*1024)

  const int lane = tid & 63;
  const int wid = tid >> 6;
  const int wr = wid >> 1, wcid = wid & 1;
  const int fr = lane & 15;                // fragment row/col
  const int kg = lane >> 4;                // k-group: k = kg*8..kg*8+7

  f32x4 acc[4][4];
#pragma unroll
  for (int m = 0; m < 4; ++m)
#pragma unroll
    for (int n = 0; n < 4; ++n) acc[m][n] = (f32x4){0.f, 0.f, 0.f, 0.f};

  for (int k0 = 0; k0 < 2048; k0 += 32) {
    __syncthreads();   // prior ds_reads done before overwrite
#pragma unroll
    for (int i = 0; i < 2; ++i) {
      const unsigned short* ga = Asrc + (size_t)(r0 + i * 64) * 2048 + k0 + c0;
      __builtin_amdgcn_global_load_lds(
          (const __attribute__((address_space(1))) void*)ga,
          (__attribute__((address_space(3))) void*)((char*)lA + i * 4096 + ldsbase),
          16, 0, 0);
      const unsigned short* gb = Bsrc + (size_t)(r0 + i * 64) * 2048 + k0 + c0;
      __builtin_amdgcn_global_load_lds(
          (const __attribute__((address_space(1))) void*)gb,
          (__attribute__((address_space(3))) void*)((char*)lB + i * 4096 + ldsbase),
          16, 0, 0);
    }
    __syncthreads();   // compiler drains vmcnt before s_barrier

    bf16x8 fa[4], fb[4];
#pragma unroll
    for (int m = 0; m < 4; ++m) {
      int row = wr * 64 + m * 16 + fr;
      fa[m] = *(const bf16x8*)&lA[row * 32 + kg * 8];
    }
#pragma unroll
    for (int n = 0; n < 4; ++n) {
      int col = wcid * 64 + n * 16 + fr;
      fb[n] = *(const bf16x8*)&lB[col * 32 + kg * 8];
    }
#pragma unroll
    for (int m = 0; m < 4; ++m)
#pragma unroll
      for (int n = 0; n < 4; ++n)
        acc[m][n] = __builtin_amdgcn_mfma_f32_16x16x32_bf16(fa[m], fb[n], acc[m][n], 0, 0, 0);
  }

  // epilogue: C/D layout col=lane&15, row=(lane>>4)*4+q  [m89-verified]
  const int rq = kg * 4;
#pragma unroll
  for (int m = 0; m < 4; ++m) {
    int grow = brow + wr * 64 + m * 16 + rq;
#pragma unroll
    for (int n = 0; n < 4; ++n) {
      int gcol = bcol + wcid * 64 + n * 16 + fr;
      if (!isBC) {
        float bv = bias[gcol];
#pragma unroll
        for (int q = 0; q < 4; ++q) {
          float v = acc[m][n][q] + bv;
          v = fmaxf(v, 0.f) + log1pf(__expf(-fabsf(v)));   // softplus
          Delta[(size_t)(grow + q) * 2048 + gcol] = v;
        }
      } else {
#pragma unroll
        for (int q = 0; q < 4; ++q)
          BC[(size_t)(grow + q) * 128 + gcol] = acc[m][n][q];
      }
    }
  }
}

// ---- pointwise state update: 4 lanes per (b,d), one float4 (4 states) each
__global__ __launch_bounds__(256) void pointwise_kernel(
    const float* __restrict__ x, const float* __restrict__ sp,
    const float* __restrict__ A_log, const float* __restrict__ BCb,
    const float* __restrict__ Delta, const float* __restrict__ Dp,
    float* __restrict__ y, float* __restrict__ st) {
  int t = blockIdx.x * 256 + threadIdx.x;   // B*D*4 = 16,777,216 threads
  int sg = t & 3;
  int d = (t >> 2) & 2047;
  int b = t >> 13;
  int bd = (b << 11) + d;
  float delta = Delta[bd];
  float xv = x[bd];
  float4 spv = ((const float4*)sp)[t];
  float4 al  = ((const float4*)A_log)[(d << 2) + sg];
  float4 bt  = ((const float4*)BCb)[(b << 5) + sg];        // B_t[b][sg*4..]
  float4 ct  = ((const float4*)BCb)[(b << 5) + 4 + sg];    // C_t[b][sg*4..]
  float dx = delta * xv;
  float4 s;
  s.x = __expf(-delta * __expf(al.x)) * spv.x + dx * bt.x;
  s.y = __expf(-delta * __expf(al.y)) * spv.y + dx * bt.y;
  s.z = __expf(-delta * __expf(al.z)) * spv.z + dx * bt.z;
  s.w = __expf(-delta * __expf(al.w)) * spv.w + dx * bt.w;
  ((float4*)st)[t] = s;
  float p = s.x * ct.x + s.y * ct.y + s.z * ct.z + s.w * ct.w;
  p += __shfl_xor(p, 1, 4);
  p += __shfl_xor(p, 2, 4);
  if (sg == 0) y[bd] = p + Dp[d] * xv;
}

extern "C" void kernel_launch(void* const* d_in, const int* in_sizes, int n_in,
                              void* d_out, int out_size, void* d_ws, size_t ws_size,
                              hipStream_t stream) {
  const float* x    = (const float*)d_in[0];
  const float* sp   = (const float*)d_in[1];
  const float* alog = (const float*)d_in[2];
  const float* wb   = (const float*)d_in[3];
  const float* wc   = (const float*)d_in[4];
  const float* wd   = (const float*)d_in[5];
  const float* bdel = (const float*)d_in[6];
  const float* dp   = (const float*)d_in[7];
  float* y  = (float*)d_out;                              // (B, D)
  float* st = (float*)d_out + (size_t)BATCH * D_MODEL;    // (B, D, S)

  char* ws = (char*)d_ws;
  unsigned short* x_bf = (unsigned short*)ws;               // 8 MB
  unsigned short* w_bf = (unsigned short*)(ws + 8388608);   // 8 MB
  unsigned short* wbc  = (unsigned short*)(ws + 16777216);  // 512 KB
  float* Delta = (float*)(ws + 17301504);                   // 16 MB
  float* BC    = (float*)(ws + 34078720);                   // 1 MB

  prep_kernel<<<4224, 256, 0, stream>>>(x, wd, wb, wc, x_bf, w_bf, wbc);
  gemm_kernel<<<dim3(16, 17), 256, 0, stream>>>(x_bf, w_bf, wbc, bdel, Delta, BC);
  pointwise_kernel<<<65536, 256, 0, stream>>>(x, sp, alog, BC, Delta, dp, y, st);
}